// Round 1
// baseline (90.957 us; speedup 1.0000x reference)
//
#include <hip/hip_runtime.h>
#include <math.h>

#define NN 32
#define CC 32
#define DDIM 16
#define MM 196
#define OO 10
#define NEPS 1e-6f
#define LAMf 0.01f

// ws layout (floats):
//   gv_buf  [NN][OO][16]        off 0       size 5120
//   S_part  [NN][CC][OO]        off 5120    size 10240
//   A_part  [NN][CC][OO][16]    off 15360   size 163840
//   T_part  [NN][CC][OO]        off 179200  size 10240
// total 189440 floats = 758 KB

#define LP_STRIDE 17   // pad to avoid 32-way LDS bank conflicts on stride-16 stores
#define R_STRIDE 11

template<int PHASE>   // 0: first iter (gsrc = g, r *= 1/10), 1: mid, 2: last (also accumulate T)
__global__ __launch_bounds__(256) void accum_kernel(
    const float* __restrict__ l,
    const float* __restrict__ gsrc,
    const float* __restrict__ weight,
    float* __restrict__ S_part,
    float* __restrict__ A_part,
    float* __restrict__ T_part)
{
    const int n = blockIdx.x / CC;
    const int c = blockIdx.x % CC;
    const int tid = threadIdx.x;

    __shared__ float Wl[OO * 16];
    __shared__ float gvl[OO * 16];
    __shared__ float lp_s[MM * LP_STRIDE];
    __shared__ float r_s[MM * R_STRIDE];
    __shared__ float nv_s[MM * R_STRIDE];

    if (tid < OO * 16) {
        Wl[tid] = weight[c * OO * 16 + tid];
        gvl[tid] = gsrc[n * OO * 16 + tid];
    }
    __syncthreads();

    const int m = tid;
    if (m < MM) {
        float lp[16];
        const float* lbase = l + (size_t)(n * CC + c) * DDIM * MM + m;
        #pragma unroll
        for (int dd = 0; dd < 16; ++dd) {
            lp[dd] = lbase[dd * MM];          // coalesced across threads (m contiguous)
            lp_s[m * LP_STRIDE + dd] = lp[dd];
        }
        float rn[OO];
        float rd = 0.f;
        #pragma unroll
        for (int o = 0; o < OO; ++o) {
            float dist = 0.f, nv = 0.f;
            #pragma unroll
            for (int i = 0; i < 4; ++i) {
                #pragma unroll
                for (int k = 0; k < 4; ++k) {
                    float v = 0.f;
                    #pragma unroll
                    for (int j = 0; j < 4; ++j)
                        v = fmaf(lp[i * 4 + j], Wl[o * 16 + j * 4 + k], v);
                    nv = fmaf(v, v, nv);
                    float dvk = v - gvl[o * 16 + i * 4 + k];
                    dist = fmaf(dvk, dvk, dist);
                }
            }
            rn[o] = dist + NEPS;           // r_n = ||V-g||^2 + EPS  (M=2 -> exponent is exactly 2)
            rd += 1.0f / rn[o];
            if (PHASE == 2) nv_s[m * R_STRIDE + o] = nv;
        }
        #pragma unroll
        for (int o = 0; o < OO; ++o) {
            float t = 1.0f / (rn[o] * rd);
            float r = t * t;               // (1/(r_n*r_d))^M, M=2
            if (PHASE == 0) r *= 0.1f;     // a_in / N_CLASSES
            r_s[m * R_STRIDE + o] = r;
        }
    }
    __syncthreads();

    const size_t pbase = (size_t)(n * CC + c) * OO;
    if (tid < OO * 16) {
        const int o = tid >> 4, ij = tid & 15;
        float acc = 0.f;
        for (int mm = 0; mm < MM; ++mm)
            acc = fmaf(r_s[mm * R_STRIDE + o], lp_s[mm * LP_STRIDE + ij], acc);
        A_part[pbase * 16 + tid] = acc;    // sum_m r * lp   (V-product deferred to reduce)
    } else if (tid < OO * 16 + OO) {
        const int o = tid - OO * 16;
        float s = 0.f;
        for (int mm = 0; mm < MM; ++mm)
            s += r_s[mm * R_STRIDE + o];
        S_part[pbase + o] = s;
    } else if (PHASE == 2 && tid < OO * 16 + 2 * OO) {
        const int o = tid - OO * 16 - OO;
        float t = 0.f;
        for (int mm = 0; mm < MM; ++mm)
            t = fmaf(r_s[mm * R_STRIDE + o], nv_s[mm * R_STRIDE + o], t);
        T_part[pbase + o] = t;             // sum_m r * ||V||^2
    }
}

template<int FINAL>
__global__ __launch_bounds__(256) void reduce_kernel(
    const float* __restrict__ S_part,
    const float* __restrict__ A_part,
    const float* __restrict__ T_part,
    const float* __restrict__ weight,
    const float* __restrict__ beta_a,
    float* __restrict__ gv_buf,
    float* __restrict__ d_out)
{
    const int n = blockIdx.x;
    const int tid = threadIdx.x;
    __shared__ float Sred[OO];
    __shared__ float Tred[OO];
    __shared__ float gvl[OO * 16];

    if (tid < OO * 16) {
        const int o = tid >> 4, ik = tid & 15;
        const int i = ik >> 2, k = ik & 3;
        float acc = 0.f;
        for (int c = 0; c < CC; ++c) {
            const float* Ap = A_part + ((size_t)(n * CC + c) * OO + o) * 16;
            const float* Wp = weight + (c * OO + o) * 16;
            #pragma unroll
            for (int j = 0; j < 4; ++j)
                acc = fmaf(Ap[i * 4 + j], Wp[j * 4 + k], acc);   // UV = sum_c (sum_m r*lp) @ W
        }
        gvl[tid] = acc;
    } else if (tid < OO * 16 + OO) {
        const int o = tid - OO * 16;
        float s = 0.f;
        for (int c = 0; c < CC; ++c)
            s += S_part[(size_t)(n * CC + c) * OO + o];
        Sred[o] = s + NEPS;                 // S + EPS
        if (FINAL) {
            float t = 0.f;
            for (int c = 0; c < CC; ++c)
                t += T_part[(size_t)(n * CC + c) * OO + o];
            Tred[o] = t;
        }
    }
    __syncthreads();

    if (tid < OO * 16) {
        const int o = tid >> 4;
        const float gv = gvl[tid] / Sred[o];   // gv = UV / (S+EPS)  (exact coeff fold)
        if (FINAL) {
            d_out[NN * OO + (size_t)n * OO * 16 + tid] = gv;
            gvl[tid] = gv;
        } else {
            gv_buf[n * OO * 16 + tid] = gv;
        }
    }
    if (FINAL) {
        __syncthreads();
        if (tid < OO) {
            float g2 = 0.f;
            #pragma unroll
            for (int ik = 0; ik < 16; ++ik)
                g2 = fmaf(gvl[tid * 16 + ik], gvl[tid * 16 + ik], g2);
            const float S1 = Sred[tid];                       // = S + EPS
            // sigma = T/(S+EPS) - ||gv||^2 * (S+2EPS)/(S+EPS)   (exact)
            float sigma = Tred[tid] / S1 - g2 * (S1 + NEPS) / S1;
            sigma = fmaxf(sigma, 1e-30f);                     // guard log of cancellation dust
            const float x = LAMf * (beta_a[tid] - 0.5f * logf(sigma));
            d_out[n * OO + tid] = 1.0f / (1.0f + expf(-x));
        }
    }
}

extern "C" void kernel_launch(void* const* d_in, const int* in_sizes, int n_in,
                              void* d_out, int out_size, void* d_ws, size_t ws_size,
                              hipStream_t stream)
{
    const float* l = (const float*)d_in[0];
    const float* g = (const float*)d_in[1];
    const float* weight = (const float*)d_in[2];
    const float* beta_a = (const float*)d_in[3];
    float* out = (float*)d_out;
    float* ws = (float*)d_ws;

    float* gv_buf = ws;
    float* S_part = ws + 5120;
    float* A_part = ws + 15360;
    float* T_part = ws + 179200;

    dim3 gA(NN * CC), bA(256);
    dim3 gB(NN), bB(256);

    // it = 0 (gv source = g, r scaled by 1/N_CLASSES)
    accum_kernel<0><<<gA, bA, 0, stream>>>(l, g, weight, S_part, A_part, T_part);
    reduce_kernel<0><<<gB, bB, 0, stream>>>(S_part, A_part, T_part, weight, beta_a, gv_buf, out);
    // it = 1
    accum_kernel<1><<<gA, bA, 0, stream>>>(l, gv_buf, weight, S_part, A_part, T_part);
    reduce_kernel<0><<<gB, bB, 0, stream>>>(S_part, A_part, T_part, weight, beta_a, gv_buf, out);
    // it = 2 (+T accumulation), final reduce writes a and gv
    accum_kernel<2><<<gA, bA, 0, stream>>>(l, gv_buf, weight, S_part, A_part, T_part);
    reduce_kernel<1><<<gB, bB, 0, stream>>>(S_part, A_part, T_part, weight, beta_a, gv_buf, out);
}

// Round 3
// 41.702 us; speedup vs baseline: 2.1811x; 2.1811x over previous
//
#include <hip/hip_runtime.h>
#include <math.h>

#define NN 32
#define CC 32
#define MM 196
#define OO 10
#define MS 204          // padded m-stride (floats): 16B-aligned rows, %32=12 -> benign aliasing
#define RECSZ 192       // per-(it,n,c) record: AW[0..160), S[160..170), T[170..180)
#define NEPS 1e-6f

#define NV_OFF 589824   // rec area: 3*NN*CC*RECSZ floats; nv area: NN*CC*OO*MM floats (8 MB)

// rec(it,n,c) = ws + ((it*NN+n)*CC+c)*RECSZ       AW = (sum_m r*lp) @ W[c,o]
// nv(n,c)    = ws + NV_OFF + (n*CC+c)*OO*MM       layout [o][m], m contiguous

template<int IT>   // IT=0: direct V path, gv=g, r*=0.1 ; IT=1,2: factored path; IT=2 adds T
__global__ __launch_bounds__(256, 4) void accum_kernel(
    const float* __restrict__ l, const float* __restrict__ g,
    const float* __restrict__ weight, float* __restrict__ ws)
{
    const int n = blockIdx.x >> 5, c = blockIdx.x & 31, tid = threadIdx.x;
    __shared__ float Wl[160], gvl[160], Ablk[160];
    __shared__ float Wg[160], ggs[16], Ss[16];
    __shared__ __align__(16) float lpT[16 * MS];
    __shared__ __align__(16) float rT[OO * MS];
    __shared__ __align__(16) float pT[OO * MS];   // IT==2: r*||V||^2 products

    if (tid < 160) Wl[tid] = weight[c * 160 + tid];

    if constexpr (IT == 0) {
        if (tid < 160) gvl[tid] = g[n * 160 + tid];
    } else {
        // inline reduce of previous iteration's records for this n (redundant per block, L2-hot)
        const float* base = ws + ((size_t)((IT - 1) * NN + n) * CC) * RECSZ;
        if (tid < 160) {
            float u = 0.f;
            for (int cc2 = 0; cc2 < CC; ++cc2) u += base[cc2 * RECSZ + tid];
            Ablk[tid] = u;                                  // UV (temp)
        } else if (tid < 170) {
            float s = 0.f;
            for (int cc2 = 0; cc2 < CC; ++cc2) s += base[cc2 * RECSZ + 160 + (tid - 160)];
            Ss[tid - 160] = s + NEPS;
        }
        __syncthreads();                                    // also covers Wl
        if (tid < 160) gvl[tid] = Ablk[tid] / Ss[tid >> 4]; // gv = UV/(S+EPS)
        __syncthreads();
        if (tid < 160) {                                    // Wg[o,i,j] = sum_k W[o,j,k]*gv[o,i,k]
            const int o = tid >> 4, i = (tid >> 2) & 3, j = tid & 3;
            float acc = 0.f;
            #pragma unroll
            for (int k = 0; k < 4; ++k)
                acc = fmaf(Wl[o * 16 + j * 4 + k], gvl[o * 16 + i * 4 + k], acc);
            Wg[tid] = acc;
        } else if (tid >= 160 && tid < 170) {
            const int o = tid - 160;
            float s = 0.f;
            #pragma unroll
            for (int e = 0; e < 16; ++e) s = fmaf(gvl[o * 16 + e], gvl[o * 16 + e], s);
            ggs[o] = s;                                     // ||gv_o||^2
        }
    }

    const bool act = tid < MM;
    const int m = tid;
    float lp[16];
    if (act) {
        const float* lbase = l + ((size_t)(n * CC + c)) * (16 * MM) + m;
        #pragma unroll
        for (int dd = 0; dd < 16; ++dd) {
            lp[dd] = lbase[dd * MM];        // coalesced (m contiguous across lanes)
            lpT[dd * MS + m] = lp[dd];
        }
    }
    __syncthreads();   // gvl/Wg/ggs/lpT ready

    if (act) {
        float* nvg = ws + NV_OFF + (size_t)(n * CC + c) * (OO * MM);
        float rn[OO], nvl[OO];
        float rd = 0.f;
        #pragma unroll
        for (int o = 0; o < OO; ++o) {
            float dist;
            if constexpr (IT == 0) {
                float nvv = 0.f; dist = 0.f;
                #pragma unroll
                for (int i = 0; i < 4; ++i) {
                    #pragma unroll
                    for (int k = 0; k < 4; ++k) {
                        float v = 0.f;
                        #pragma unroll
                        for (int j = 0; j < 4; ++j)
                            v = fmaf(lp[i * 4 + j], Wl[o * 16 + j * 4 + k], v);
                        nvv = fmaf(v, v, nvv);
                        float dv = v - gvl[o * 16 + i * 4 + k];
                        dist = fmaf(dv, dv, dist);
                    }
                }
                nvg[o * MM + m] = nvv;      // persist ||V||^2 for iters 1-2
            } else {
                const float nvv = nvg[o * MM + m];
                nvl[o] = nvv;
                const float4* wg4 = (const float4*)&Wg[o * 16];
                float4 w0 = wg4[0], w1 = wg4[1], w2 = wg4[2], w3 = wg4[3];
                float dot = 0.f;
                dot = fmaf(lp[0],  w0.x, dot); dot = fmaf(lp[1],  w0.y, dot);
                dot = fmaf(lp[2],  w0.z, dot); dot = fmaf(lp[3],  w0.w, dot);
                dot = fmaf(lp[4],  w1.x, dot); dot = fmaf(lp[5],  w1.y, dot);
                dot = fmaf(lp[6],  w1.z, dot); dot = fmaf(lp[7],  w1.w, dot);
                dot = fmaf(lp[8],  w2.x, dot); dot = fmaf(lp[9],  w2.y, dot);
                dot = fmaf(lp[10], w2.z, dot); dot = fmaf(lp[11], w2.w, dot);
                dot = fmaf(lp[12], w3.x, dot); dot = fmaf(lp[13], w3.y, dot);
                dot = fmaf(lp[14], w3.z, dot); dot = fmaf(lp[15], w3.w, dot);
                dist = fmaxf(nvv - 2.f * dot + ggs[o], 0.f);   // ||V-gv||^2, guarded
            }
            rn[o] = dist + NEPS;
            rd += 1.0f / rn[o];
        }
        #pragma unroll
        for (int o = 0; o < OO; ++o) {
            float t = 1.0f / (rn[o] * rd);
            float r = t * t;
            if constexpr (IT == 0) r *= 0.1f;      // a_in / N_CLASSES
            rT[o * MS + m] = r;
            if constexpr (IT == 2) pT[o * MS + m] = r * nvl[o];
        }
    }
    __syncthreads();   // rT (and pT) ready

    float* rec = ws + ((size_t)(IT * NN + n) * CC + c) * RECSZ;
    if (tid < 160) {                       // A[o][ij] = sum_m r*lp  (float4 LDS reads)
        const int o = tid >> 4, ij = tid & 15;
        const float4* rp  = (const float4*)&rT[o * MS];
        const float4* lpp = (const float4*)&lpT[ij * MS];
        float acc = 0.f;
        for (int mm = 0; mm < MM / 4; ++mm) {
            float4 r4 = rp[mm], l4 = lpp[mm];
            acc = fmaf(r4.x, l4.x, acc);
            acc = fmaf(r4.y, l4.y, acc);
            acc = fmaf(r4.z, l4.z, acc);
            acc = fmaf(r4.w, l4.w, acc);
        }
        Ablk[tid] = acc;
    } else if (tid >= 192 && tid < 202) {  // S (wave 3)
        const int o = tid - 192;
        const float4* rp = (const float4*)&rT[o * MS];
        float s = 0.f;
        for (int mm = 0; mm < MM / 4; ++mm) {
            float4 r4 = rp[mm];
            s += (r4.x + r4.y) + (r4.z + r4.w);
        }
        rec[160 + o] = s;
    } else if (IT == 2 && tid >= 208 && tid < 218) {   // T = sum_m r*||V||^2
        const int o = tid - 208;
        const float4* pp = (const float4*)&pT[o * MS];
        float t = 0.f;
        for (int mm = 0; mm < MM / 4; ++mm) {
            float4 p4 = pp[mm];
            t += (p4.x + p4.y) + (p4.z + p4.w);
        }
        rec[170 + o] = t;
    }
    __syncthreads();   // Ablk ready
    if (tid < 160) {   // AW = A @ W[c,o]
        const int o = tid >> 4, ik = tid & 15, i = ik >> 2, k = ik & 3;
        float aw = 0.f;
        #pragma unroll
        for (int j = 0; j < 4; ++j)
            aw = fmaf(Ablk[o * 16 + i * 4 + j], Wl[o * 16 + j * 4 + k], aw);
        rec[tid] = aw;
    }
}

__global__ __launch_bounds__(256) void finalize_kernel(
    const float* __restrict__ beta_a, float* __restrict__ out, const float* __restrict__ ws)
{
    const int n = blockIdx.x, tid = threadIdx.x;
    __shared__ float Sred[OO], Tred[OO], gvl[160];

    const float* base = ws + ((size_t)(2 * NN + n) * CC) * RECSZ;
    float uacc = 0.f;
    if (tid < 160) {
        for (int cc2 = 0; cc2 < CC; ++cc2) uacc += base[cc2 * RECSZ + tid];
    } else if (tid < 170) {
        const int o = tid - 160;
        float s = 0.f, t = 0.f;
        for (int cc2 = 0; cc2 < CC; ++cc2) {
            s += base[cc2 * RECSZ + 160 + o];
            t += base[cc2 * RECSZ + 170 + o];
        }
        Sred[o] = s + NEPS;
        Tred[o] = t;
    }
    __syncthreads();
    if (tid < 160) {
        const float gvv = uacc / Sred[tid >> 4];
        out[NN * OO + (size_t)n * 160 + tid] = gvv;
        gvl[tid] = gvv;
    }
    __syncthreads();
    if (tid < OO) {
        float g2 = 0.f;
        #pragma unroll
        for (int e = 0; e < 16; ++e) g2 = fmaf(gvl[tid * 16 + e], gvl[tid * 16 + e], g2);
        const float S1 = Sred[tid];
        // sigma = T/(S+EPS) - ||gv||^2*(S+2EPS)/(S+EPS)   (exact coeff-fold algebra)
        float sigma = Tred[tid] / S1 - g2 * (S1 + NEPS) / S1;
        sigma = fmaxf(sigma, 1e-30f);
        const float x = 0.01f * (beta_a[tid] - 0.5f * logf(sigma));
        out[n * OO + tid] = 1.0f / (1.0f + expf(-x));
    }
}

extern "C" void kernel_launch(void* const* d_in, const int* in_sizes, int n_in,
                              void* d_out, int out_size, void* d_ws, size_t ws_size,
                              hipStream_t stream)
{
    const float* l      = (const float*)d_in[0];
    const float* g      = (const float*)d_in[1];
    const float* weight = (const float*)d_in[2];
    const float* beta_a = (const float*)d_in[3];
    float* out = (float*)d_out;
    float* ws  = (float*)d_ws;

    dim3 gA(NN * CC), bA(256);
    accum_kernel<0><<<gA, bA, 0, stream>>>(l, g, weight, ws);
    accum_kernel<1><<<gA, bA, 0, stream>>>(l, g, weight, ws);
    accum_kernel<2><<<gA, bA, 0, stream>>>(l, g, weight, ws);
    finalize_kernel<<<dim3(NN), dim3(256), 0, stream>>>(beta_a, out, ws);
}